// Round 1
// baseline (9636.128 us; speedup 1.0000x reference)
//
#include <hip/hip_runtime.h>
#include <hip/hip_bf16.h>
#include <hip/hip_fp16.h>

typedef _Float16 v2h __attribute__((ext_vector_type(2)));

__device__ __forceinline__ float fdot2u(unsigned int a, unsigned int b, float c){
  return __builtin_amdgcn_fdot2(__builtin_bit_cast(v2h, a), __builtin_bit_cast(v2h, b), c, false);
}
__device__ __forceinline__ unsigned int packh2(float a, float b){
  union{ _Float16 h[2]; unsigned int u; } z;
  z.h[0] = (_Float16)a; z.h[1] = (_Float16)b; return z.u;
}
__device__ __forceinline__ float h2f(unsigned short s){
  return (float)__builtin_bit_cast(_Float16, s);
}
__device__ __forceinline__ float sigf(float x){
  return __builtin_amdgcn_rcpf(1.0f + __builtin_amdgcn_exp2f(-1.44269504f*x));
}
__device__ __forceinline__ float tanhf_(float x){
  return 2.0f*__builtin_amdgcn_rcpf(1.0f + __builtin_amdgcn_exp2f(-2.88539008f*x)) - 1.0f;
}

// ---------------- Kernel A: weight conversion / bias fuse ----------------
__global__ void prep_kernel(const float* __restrict__ Whh, const float* __restrict__ Wfc,
                            const float* __restrict__ bih, const float* __restrict__ bhh,
                            unsigned int* __restrict__ whh16, unsigned int* __restrict__ wfc16,
                            float* __restrict__ bsum){
  int i = blockIdx.x*256 + threadIdx.x;
  if (i < 131072){                       // W_hh (1024 x 256) -> f16 pair dwords (1024 x 128)
    int r = i >> 7, d = i & 127;
    whh16[i] = packh2(Whh[r*256 + 2*d], Whh[r*256 + 2*d + 1]);
  } else if (i < 139264){                // W_fc (64 x 256) -> (64 x 128)
    int j = i - 131072; int o = j >> 7, d = j & 127;
    wfc16[j] = packh2(Wfc[o*256 + 2*d], Wfc[o*256 + 2*d + 1]);
  } else if (i < 140288){                // bsum = b_ih + b_hh
    int g = i - 139264;
    bsum[g] = bih[g] + bhh[g];
  }
}

// ---------------- Kernel B: x_proj = x @ W_ih^T + bsum (f16 out) ----------------
#define XS 68
__global__ __launch_bounds__(256) void xproj_kernel(const float* __restrict__ x,
                          const float* __restrict__ Wih,
                          const float* __restrict__ bsum, unsigned int* __restrict__ xproj){
  __shared__ unsigned int lx[128*XS];
  __shared__ unsigned int lw[64*XS];
  __shared__ float lb[64];
  int t  = threadIdx.x;
  int bt0 = blockIdx.x*128, g0 = blockIdx.y*64;
  int rr = t >> 4, cc = t & 15;
  #pragma unroll
  for (int it=0; it<8; ++it){            // stage x tile (128 rows x 128 f32 -> f16 pairs)
    int row = rr + it*16;
    const float4* s = (const float4*)(x + (size_t)(bt0+row)*128 + cc*8);
    float4 a = s[0], b = s[1];
    uint4 w; w.x=packh2(a.x,a.y); w.y=packh2(a.z,a.w); w.z=packh2(b.x,b.y); w.w=packh2(b.z,b.w);
    *(uint4*)&lx[row*XS + cc*4] = w;
  }
  #pragma unroll
  for (int it=0; it<4; ++it){            // stage W tile (64 rows)
    int row = rr + it*16;
    const float4* s = (const float4*)(Wih + (size_t)(g0+row)*128 + cc*8);
    float4 a = s[0], b = s[1];
    uint4 w; w.x=packh2(a.x,a.y); w.y=packh2(a.z,a.w); w.z=packh2(b.x,b.y); w.w=packh2(b.z,b.w);
    *(uint4*)&lw[row*XS + cc*4] = w;
  }
  if (t < 64) lb[t] = bsum[g0 + t];
  __syncthreads();

  float acc[8][4];
  #pragma unroll
  for (int j=0;j<8;++j)
    #pragma unroll
    for (int i=0;i<4;++i) acc[j][i]=0.f;

  #pragma unroll
  for (int d4=0; d4<16; ++d4){
    uint4 wv[4], xv[8];
    #pragma unroll
    for (int i=0;i<4;++i) wv[i] = *(const uint4*)&lw[(cc*4+i)*XS + d4*4];
    #pragma unroll
    for (int j=0;j<8;++j) xv[j] = *(const uint4*)&lx[(rr*8+j)*XS + d4*4];
    #pragma unroll
    for (int j=0;j<8;++j){
      #pragma unroll
      for (int i=0;i<4;++i){
        float a = acc[j][i];
        a = fdot2u(xv[j].x, wv[i].x, a);
        a = fdot2u(xv[j].y, wv[i].y, a);
        a = fdot2u(xv[j].z, wv[i].z, a);
        a = fdot2u(xv[j].w, wv[i].w, a);
        acc[j][i] = a;
      }
    }
  }
  #pragma unroll
  for (int j=0;j<8;++j){
    int bt = bt0 + rr*8 + j;
    uint2 o2;
    o2.x = packh2(acc[j][0]+lb[cc*4+0], acc[j][1]+lb[cc*4+1]);
    o2.y = packh2(acc[j][2]+lb[cc*4+2], acc[j][3]+lb[cc*4+3]);
    *(uint2*)&xproj[(size_t)bt*512 + (g0>>1) + cc*2] = o2;
  }
}

// ---------------- Kernel C: recurrent LSTM (1 WG per batch, persistent over T) ----------------
#define RL4 26                 // uint4 weight groups in registers (104 dwords = 208 f16)
#define LL  24                 // weight dwords per row kept in LDS (48 f16)
#define LSTR 26                // LDS row stride (dwords): 2-way bank alias only
#define HOFF (1024*LSTR)       // dword offset of h double-buffer

extern "C" __global__ void __launch_bounds__(256,1) lstm_kernel(
    const unsigned int* __restrict__ xproj, const unsigned int* __restrict__ whh16,
    unsigned short* __restrict__ h_all)
{
  extern __shared__ unsigned int lds[];
  const int u = threadIdx.x;     // hidden unit index; rows u, 256+u, 512+u, 768+u (i,f,g,o)
  const int b = blockIdx.x;      // batch

  uint4 w4[4][RL4];
  #pragma unroll
  for (int r=0;r<4;++r){
    int R = r*256 + u;
    const uint4* src = (const uint4*)(whh16 + (size_t)R*128);
    #pragma unroll
    for (int d4=0; d4<RL4; ++d4) w4[r][d4] = src[d4];
    #pragma unroll
    for (int d=0; d<LL; ++d) lds[R*LSTR + d] = whh16[(size_t)R*128 + RL4*4 + d];
  }
  if (u < 128) lds[HOFF + u] = 0u;   // h buffer 0 = zeros (t=0 reads h=0)

  const unsigned short* xp = (const unsigned short*)xproj + (size_t)b*2048*1024;
  unsigned short xn0 = xp[u], xn1 = xp[256+u], xn2 = xp[512+u], xn3 = xp[768+u];
  float c = 0.f;
  unsigned short* hout = h_all + (size_t)b*2048*256 + u;
  __syncthreads();

  for (int t=0; t<2048; ++t){
    const int cur = t & 1;
    float a[4] = { h2f(xn0), h2f(xn1), h2f(xn2), h2f(xn3) };
    // prefetch next step's x_proj
    int tn = (t+1 < 2048) ? t+1 : 2047;
    const unsigned short* xr = xp + (size_t)tn*1024;
    xn0 = xr[u]; xn1 = xr[256+u]; xn2 = xr[512+u]; xn3 = xr[768+u];

    const unsigned int* hb = lds + HOFF + cur*128;
    #pragma unroll
    for (int d4=0; d4<RL4; ++d4){
      uint4 h4 = *(const uint4*)(hb + d4*4);
      #pragma unroll
      for (int r=0;r<4;++r){
        float t0 = a[r];
        t0 = fdot2u(w4[r][d4].x, h4.x, t0);
        t0 = fdot2u(w4[r][d4].y, h4.y, t0);
        t0 = fdot2u(w4[r][d4].z, h4.z, t0);
        t0 = fdot2u(w4[r][d4].w, h4.w, t0);
        a[r] = t0;
      }
    }
    #pragma unroll
    for (int g4=0; g4<LL/4; ++g4){
      uint4 h4 = *(const uint4*)(hb + (RL4+g4)*4);
      #pragma unroll
      for (int r=0;r<4;++r){
        const unsigned int* wl = lds + (r*256+u)*LSTR + g4*4;
        uint2 wa = *(const uint2*)(wl);
        uint2 wb = *(const uint2*)(wl+2);
        float t0 = a[r];
        t0 = fdot2u(wa.x, h4.x, t0);
        t0 = fdot2u(wa.y, h4.y, t0);
        t0 = fdot2u(wb.x, h4.z, t0);
        t0 = fdot2u(wb.y, h4.w, t0);
        a[r] = t0;
      }
    }
    float iv = sigf(a[0]);
    float fv = sigf(a[1]);
    float gv = tanhf_(a[2]);
    float ov = sigf(a[3]);
    c = fv*c + iv*gv;
    float h = ov * tanhf_(c);
    unsigned short hh = __builtin_bit_cast(unsigned short, (_Float16)h);
    ((unsigned short*)(lds + HOFF + (cur^1)*128))[u] = hh;  // next step's h (f16)
    hout[(size_t)t*256] = hh;                                // h_all for fc phase
    __syncthreads();
  }
}

// ---------------- Kernel D: logits = h @ W_fc^T + b_fc ; softmax over O=64 ----------------
__global__ __launch_bounds__(1024) void fc_softmax_kernel(const unsigned short* __restrict__ h_all,
      const unsigned int* __restrict__ wfc16, const float* __restrict__ bfc,
      float* __restrict__ out){
  __shared__ unsigned int lwf[64*132];
  __shared__ unsigned int lh[16*132];
  int t = threadIdx.x;
  int bt0 = blockIdx.x*16;
  {
    const uint4* s = (const uint4*)(wfc16 + (size_t)t*8);
    uint4 a = s[0], b = s[1];
    unsigned int* dst = &lwf[(t>>4)*132 + (t&15)*8];
    *(uint4*)dst = a; *(uint4*)(dst+4) = b;
  }
  {
    int row = t>>6, col = (t&63)*2;
    const unsigned int* hsrc = (const unsigned int*)h_all;
    uint2 v = *(const uint2*)(hsrc + (size_t)(bt0+row)*128 + col);
    *(uint2*)&lh[row*132 + col] = v;
  }
  __syncthreads();
  int w = t>>6, o = t&63;
  int bt = bt0 + w;
  float acc = bfc[o];
  #pragma unroll
  for (int d4=0; d4<32; ++d4){
    uint4 hq = *(const uint4*)&lh[w*132 + d4*4];
    uint4 wq = *(const uint4*)&lwf[o*132 + d4*4];
    acc = fdot2u(wq.x, hq.x, acc);
    acc = fdot2u(wq.y, hq.y, acc);
    acc = fdot2u(wq.z, hq.z, acc);
    acc = fdot2u(wq.w, hq.w, acc);
  }
  float m = acc;
  #pragma unroll
  for (int off=32; off>=1; off>>=1) m = fmaxf(m, __shfl_xor(m, off));
  float e = __builtin_amdgcn_exp2f(1.44269504f*(acc - m));
  float s = e;
  #pragma unroll
  for (int off=32; off>=1; off>>=1) s += __shfl_xor(s, off);
  out[(size_t)bt*64 + o] = e * __builtin_amdgcn_rcpf(s);
}

// ---------------- launch ----------------
extern "C" void kernel_launch(void* const* d_in, const int* in_sizes, int n_in,
                              void* d_out, int out_size, void* d_ws, size_t ws_size,
                              hipStream_t stream){
  const float* x   = (const float*)d_in[0];
  const float* Wih = (const float*)d_in[1];
  const float* Whh = (const float*)d_in[2];
  const float* bih = (const float*)d_in[3];
  const float* bhh = (const float*)d_in[4];
  const float* Wfc = (const float*)d_in[5];
  const float* bfc = (const float*)d_in[6];
  float* out = (float*)d_out;

  char* ws = (char*)d_ws;
  unsigned int*   xproj = (unsigned int*)ws;                         // 128 MB (f16 pairs)
  unsigned short* h_all = (unsigned short*)(ws + 134217728);         // 32 MB (f16)
  unsigned int*   whh16 = (unsigned int*)(ws + 134217728 + 33554432);// 512 KB
  unsigned int*   wfc16 = whh16 + 131072;                            // 32 KB
  float*          bsum  = (float*)(wfc16 + 8192);                    // 4 KB

  prep_kernel<<<548, 256, 0, stream>>>(Whh, Wfc, bih, bhh, whh16, wfc16, bsum);
  dim3 gb(512, 16);
  xproj_kernel<<<gb, 256, 0, stream>>>(x, Wih, bsum, xproj);
  int dyn = (HOFF + 256) * 4;   // 107,520 B dynamic LDS
  hipFuncSetAttribute((const void*)lstm_kernel, hipFuncAttributeMaxDynamicSharedMemorySize, dyn);
  lstm_kernel<<<32, 256, dyn, stream>>>(xproj, whh16, h_all);
  fc_softmax_kernel<<<4096, 1024, 0, stream>>>(h_all, wfc16, bfc, out);
}